// Round 1
// 3728.689 us; speedup vs baseline: 1.1469x; 1.1469x over previous
//
#include <hip/hip_runtime.h>

#define M_DIM 4096
#define K_DIM 4096
#define N_DIM 32768
#define TOPK  64
#define NCAND 96
#define NT    (K_DIM / 64)   // 64 K-tiles of BK=64

typedef __attribute__((ext_vector_type(8))) _Float16 half8;
typedef __attribute__((ext_vector_type(4))) _Float16 half4;
typedef __attribute__((ext_vector_type(4))) float    f32x4;

#define GLDS(gp, lp) __builtin_amdgcn_global_load_lds( \
    (const __attribute__((address_space(1))) void*)(gp), \
    (__attribute__((address_space(3))) void*)(lp), 16, 0, 0)

// raw barrier / counted waits with compiler memory fences (no vmcnt drain at barriers)
#define BARX()  asm volatile("s_barrier" ::: "memory")
#define LGKM0() asm volatile("s_waitcnt lgkmcnt(0)" ::: "memory")
#define VMC6()  asm volatile("s_waitcnt vmcnt(6)" ::: "memory")
#define VMC0()  asm volatile("s_waitcnt vmcnt(0)" ::: "memory")

// ---------------- cast: fp32 -> fp16 (hi only; refine restores precision) -------
__launch_bounds__(256)
__global__ void cast_kernel(const float4* __restrict__ src, half4* __restrict__ dst, int n4) {
  int i = blockIdx.x * blockDim.x + threadIdx.x;
  int stride = gridDim.x * blockDim.x;
  for (; i < n4; i += stride) {
    float4 x = src[i];
    half4 h;
    h[0] = (_Float16)x.x; h[1] = (_Float16)x.y; h[2] = (_Float16)x.z; h[3] = (_Float16)x.w;
    dst[i] = h;
  }
}

// ---------------- encode GEMM: 256x256 tile, BK=64, 8-phase counted-vmcnt -------
// 8 waves (2M x 4N), per-wave C = 128x64. LDS = 2 buf x 4 half-slots x 16 KB.
// slot content: 0 = B rows 0-127, 1 = B rows 128-255, 2 = A rows 0-127, 3 = A rows 128-255
// Staging ledger (half h = 4t+c, c order B0,B1,A0,A1; phase g stages h = g+6):
//   tile T ph1: (T+1).A1   ph2: (T+2).B0   ph3: (T+2).B1   ph4: (T+2).A0
// Slot last-read vs overwrite-issue: B0 ph1/ph2, B1 ph1/ph3, A0 ph3/ph4, A1 ph3/next-ph1.
// Every overwrite is issued after the barrier that follows the draining lgkmcnt(0). Fence
// vmcnt(6) per tile leaves exactly 3 half-tiles (6 loads) in flight.
__launch_bounds__(512, 2)
__global__ void gemm_enc(const _Float16* __restrict__ xh, const _Float16* __restrict__ wh,
                         const float* __restrict__ b_enc, float* __restrict__ a1)
{
  __shared__ alignas(16) _Float16 lds[2 * 4 * 8192];   // 128 KiB

  const int tid  = threadIdx.x;
  const int lane = tid & 63;
  const int wave = tid >> 6;
  const int wm = wave >> 2;      // 0..1 (M half)
  const int wn = wave & 3;       // 0..3 (N quarter)

  // XCD swizzle: 2048 wgs = 8 XCD x 256. Each XCD owns 16 n-cols, walks m fastest:
  // B panel (2 MB) L2-resident per XCD, all 16 A panels (32 MB) L3-resident.
  const int bid  = blockIdx.x;
  const int xcd  = bid & 7;
  const int bi   = bid >> 3;           // 0..255
  const int ncol = xcd * 16 + (bi >> 4);
  const int mrow = bi & 15;
  const int m0 = mrow << 8;
  const int n0 = ncol << 8;

  // staging: thread t covers local row (t>>3) (+0/+64), 16B chunk (t&7).
  // LDS dest linear (gload_lds rule); source chunk pre-XOR-swizzled by row&7.
  const int srow   = tid >> 3;
  const int schunk = (tid & 7) ^ (srow & 7);
  const _Float16* pA = xh + (size_t)(m0 + srow) * K_DIM + schunk * 8;
  const _Float16* pB = wh + (size_t)(n0 + srow) * K_DIM + schunk * 8;
  const int sdst = tid * 8;            // element offset in slot (+4096 for r=1)

  // ds_read fragment offsets (elements), XOR matching the staging pre-swizzle
  const int l15 = lane & 15, l7 = lane & 7, kq = lane >> 4;
  const int c0  = kq ^ l7;
  const int ck0 = c0 * 8, ck1 = (c0 ^ 4) * 8;   // ks=0 / ks=1 chunk offsets
  const int arow = l15 * 64;
  const int brow = (wn & 1) * 4096 + l15 * 64;

  f32x4 acc[8][4];
  const f32x4 zero = {0.f, 0.f, 0.f, 0.f};
#pragma unroll
  for (int im = 0; im < 8; ++im)
#pragma unroll
    for (int jn = 0; jn < 4; ++jn) acc[im][jn] = zero;

#define STAGE(c, t) do { \
    const _Float16* sp_ = (((c) >= 2) ? pA : pB) + (size_t)((c) & 1) * 128 * K_DIM + (t) * 64; \
    _Float16* dp_ = &lds[(((((t) & 1) << 2) | (c)) << 13) + sdst]; \
    GLDS(sp_, dp_); \
    GLDS(sp_ + 64 * K_DIM, dp_ + 4096); \
  } while (0)

  half8 a_[4][2], b_[4][2];

#define LDA(mh, ab) do { \
    _Pragma("unroll") for (int mt = 0; mt < 4; ++mt) { \
      a_[mt][0] = *(const half8*)&lds[(ab) + (mh) * 4096 + mt * 1024 + arow + ck0]; \
      a_[mt][1] = *(const half8*)&lds[(ab) + (mh) * 4096 + mt * 1024 + arow + ck1]; \
    } } while (0)

#define LDB(bb) do { \
    _Pragma("unroll") for (int nt = 0; nt < 4; ++nt) { \
      b_[nt][0] = *(const half8*)&lds[(bb) + nt * 1024 + brow + ck0]; \
      b_[nt][1] = *(const half8*)&lds[(bb) + nt * 1024 + brow + ck1]; \
    } } while (0)

#define QUAD(mh, nh) do { \
    _Pragma("unroll") for (int mt = 0; mt < 4; ++mt) \
    _Pragma("unroll") for (int nt = 0; nt < 2; ++nt) { \
      acc[(mh)*4+mt][(nh)*2+nt] = __builtin_amdgcn_mfma_f32_16x16x32_f16( \
          a_[mt][0], b_[(nh)*2+nt][0], acc[(mh)*4+mt][(nh)*2+nt], 0, 0, 0); \
      acc[(mh)*4+mt][(nh)*2+nt] = __builtin_amdgcn_mfma_f32_16x16x32_f16( \
          a_[mt][1], b_[(nh)*2+nt][1], acc[(mh)*4+mt][(nh)*2+nt], 0, 0, 0); \
    } } while (0)

  // prologue: halves 0..6 (tile0 complete + tile1 B0,B1,A0); tile0 landed, 6 in flight
  STAGE(0, 0); STAGE(1, 0); STAGE(2, 0); STAGE(3, 0);
  STAGE(0, 1); STAGE(1, 1); STAGE(2, 1);
  VMC6();
  BARX();

  for (int T = 0; T < NT; ++T) {
    const int ab = (((T & 1) << 2) + 2 + wm) << 13;
    const int bb = (((T & 1) << 2) + (wn >> 1)) << 13;
    // ---- phase 1: ds_read A(mh0) + all B (16 reads), stage (T+1).A1, quad(0,0) ----
    LDA(0, ab);
    LDB(bb);
    if (T + 1 < NT) STAGE(3, T + 1);
    BARX(); LGKM0();
    __builtin_amdgcn_s_setprio(1); QUAD(0, 0); __builtin_amdgcn_s_setprio(0);
    BARX();
    // ---- phase 2: stage (T+2).B0, quad(0,1) (b regs from ph1) ----
    if (T + 2 < NT) STAGE(0, T + 2);
    BARX();
    __builtin_amdgcn_s_setprio(1); QUAD(0, 1); __builtin_amdgcn_s_setprio(0);
    BARX();
    // ---- phase 3: ds_read A(mh1), stage (T+2).B1, quad(1,0) ----
    LDA(1, ab);
    if (T + 2 < NT) STAGE(1, T + 2);
    BARX(); LGKM0();
    __builtin_amdgcn_s_setprio(1); QUAD(1, 0); __builtin_amdgcn_s_setprio(0);
    BARX();
    // ---- phase 4: stage (T+2).A0, quad(1,1), counted vmcnt fence ----
    if (T + 2 < NT) STAGE(2, T + 2);
    BARX();
    __builtin_amdgcn_s_setprio(1); QUAD(1, 1); __builtin_amdgcn_s_setprio(0);
    if (T < NT - 2) { VMC6(); } else { VMC0(); }
    BARX();
  }

  // epilogue: C row = (lane>>4)*4 + reg, col = lane&15 (same convention as verified m97 kernel)
  const int col = lane & 15;
  const int r4  = (lane >> 4) << 2;
#pragma unroll
  for (int nt = 0; nt < 4; ++nt) {
    const int gc = n0 + wn * 64 + nt * 16 + col;
    const float bias = b_enc[gc];
#pragma unroll
    for (int mt = 0; mt < 8; ++mt) {
#pragma unroll
      for (int r = 0; r < 4; ++r) {
        const int gr = m0 + wm * 128 + mt * 16 + r4 + r;
        a1[(size_t)gr * N_DIM + gc] = acc[mt][nt][r] + bias;
      }
    }
  }
#undef STAGE
#undef LDA
#undef LDB
#undef QUAD
}

// ---------------- top-96 per row on fp16-approx acts: bitwise radix select -------
#define TK_THREADS 512
#define TK_PER 64   // 32768 / 512
__launch_bounds__(512)
__global__ void topk_kernel(const float* __restrict__ a1, int* __restrict__ cand)
{
  const int row = blockIdx.x;
  const float* pr = a1 + (size_t)row * N_DIM;
  const int tid = threadIdx.x;

  unsigned u[TK_PER];
#pragma unroll
  for (int i = 0; i < TK_PER; ++i) {
    union { float f; unsigned b; } c;
    c.f = pr[i * TK_THREADS + tid];
    u[i] = (c.b & 0x80000000u) ? ~c.b : (c.b | 0x80000000u);  // order-preserving key
  }

  __shared__ int red[8];
  unsigned prefix = 0;
  int needed = NCAND;
  for (int bit = 31; bit >= 0; --bit) {
    unsigned want = (prefix >> bit) | 1u;
    int cnt = 0;
#pragma unroll
    for (int i = 0; i < TK_PER; ++i) cnt += ((u[i] >> bit) == want) ? 1 : 0;
    for (int off = 32; off > 0; off >>= 1) cnt += __shfl_down(cnt, off);
    if ((tid & 63) == 0) red[tid >> 6] = cnt;
    __syncthreads();
    int total = red[0] + red[1] + red[2] + red[3] + red[4] + red[5] + red[6] + red[7];
    __syncthreads();
    if (total >= needed) prefix |= (1u << bit);
    else needed -= total;
  }
  __shared__ int c_gt, c_tie;
  if (tid == 0) { c_gt = 0; c_tie = 0; }
  __syncthreads();
#pragma unroll
  for (int i = 0; i < TK_PER; ++i) {
    if (u[i] > prefix) {
      int p = atomicAdd(&c_gt, 1);
      cand[row * NCAND + p] = i * TK_THREADS + tid;
    }
  }
  __syncthreads();
  int base = c_gt;
#pragma unroll
  for (int i = 0; i < TK_PER; ++i) {
    if (u[i] == prefix) {
      int t = atomicAdd(&c_tie, 1);
      if (t < needed) cand[row * NCAND + base + t] = i * TK_THREADS + tid;
    }
  }
}

// ---------------- refine: exact fp32 acts for 96 cands, exact top-64 ------------
__launch_bounds__(256)
__global__ void refine_kernel(const float* __restrict__ x, const float* __restrict__ W,
                              const float* __restrict__ b_enc, const int* __restrict__ cand,
                              int* __restrict__ tk_idx, float* __restrict__ tk_val)
{
  const int row = blockIdx.x;
  const int tid = threadIdx.x, lane = tid & 63, wave = tid >> 6;
  __shared__ float svals[NCAND];
  __shared__ int   sidx[NCAND];
  __shared__ int   spos;

  const float* xr = x + (size_t)row * K_DIM;
  float4 xv[16];
#pragma unroll
  for (int c = 0; c < 16; ++c) xv[c] = *(const float4*)(xr + c * 256 + lane * 4);

  for (int j = wave; j < NCAND; j += 4) {
    int cj = cand[row * NCAND + j];
    const float* wr = W + (size_t)cj * K_DIM;
    float acc = 0.f;
#pragma unroll
    for (int c = 0; c < 16; ++c) {
      float4 wv = *(const float4*)(wr + c * 256 + lane * 4);
      acc += xv[c].x * wv.x + xv[c].y * wv.y + xv[c].z * wv.z + xv[c].w * wv.w;
    }
#pragma unroll
    for (int off = 32; off > 0; off >>= 1) acc += __shfl_down(acc, off, 64);
    if (lane == 0) { svals[j] = acc + b_enc[cj]; sidx[j] = cj; }
  }
  if (tid == 0) spos = 0;
  __syncthreads();

  if (tid < NCAND) {
    float v = svals[tid];
    int myidx = sidx[tid];
    int rank = 0;
    for (int i = 0; i < NCAND; ++i) {
      float vi = svals[i];
      rank += (vi > v || (vi == v && sidx[i] < myidx)) ? 1 : 0;  // lax.top_k tie-break
    }
    if (rank < TOPK) {
      int p = atomicAdd(&spos, 1);
      tk_idx[row * TOPK + p] = myidx;
      tk_val[row * TOPK + p] = v;
    }
  }
}

// ---------------- sparse tied-weight decode: z2 = sum val_j * W[idx_j,:] + b_dec --
__launch_bounds__(256)
__global__ void decode_kernel(const _Float16* __restrict__ wh, const int* __restrict__ tk_idx,
                              const float* __restrict__ tk_val, const float* __restrict__ b_dec,
                              float* __restrict__ out)
{
  const int row = blockIdx.x, tid = threadIdx.x;
  __shared__ int   sidx[TOPK];
  __shared__ float sval[TOPK];
  if (tid < TOPK) { sidx[tid] = tk_idx[row * TOPK + tid]; sval[tid] = tk_val[row * TOPK + tid]; }
  __syncthreads();

  const int c0 = tid * 8;
  const int c1 = (tid + 256) * 8;
  float acc0[8], acc1[8];
#pragma unroll
  for (int e = 0; e < 8; ++e) { acc0[e] = b_dec[c0 + e]; acc1[e] = b_dec[c1 + e]; }

  for (int j = 0; j < TOPK; ++j) {
    const _Float16* wr = wh + (size_t)sidx[j] * K_DIM;
    half8 w0 = *(const half8*)(wr + c0);
    half8 w1 = *(const half8*)(wr + c1);
    float v = sval[j];
#pragma unroll
    for (int e = 0; e < 8; ++e) { acc0[e] += v * (float)w0[e]; acc1[e] += v * (float)w1[e]; }
  }
  float* po = out + (size_t)row * K_DIM;
#pragma unroll
  for (int e = 0; e < 8; ++e) { po[c0 + e] = acc0[e]; po[c1 + e] = acc1[e]; }
}

extern "C" void kernel_launch(void* const* d_in, const int* in_sizes, int n_in,
                              void* d_out, int out_size, void* d_ws, size_t ws_size,
                              hipStream_t stream) {
  const float* x     = (const float*)d_in[0];
  const float* W     = (const float*)d_in[1];
  const float* b_enc = (const float*)d_in[2];
  const float* b_dec = (const float*)d_in[3];

  // workspace carve (~840 MB)
  _Float16* x_h = (_Float16*)d_ws;
  _Float16* w_h = x_h + (size_t)M_DIM * K_DIM;
  float*    a1  = (float*)(w_h + (size_t)N_DIM * K_DIM);
  int*      cand = (int*)(a1 + (size_t)M_DIM * N_DIM);
  int*      tk_idx = cand + (size_t)M_DIM * NCAND;
  float*    tk_val = (float*)(tk_idx + M_DIM * TOPK);

  cast_kernel<<<4096, 256, 0, stream>>>((const float4*)x, (half4*)x_h,
                                        (int)((size_t)M_DIM * K_DIM / 4));
  cast_kernel<<<8192, 256, 0, stream>>>((const float4*)W, (half4*)w_h,
                                        (int)((size_t)N_DIM * K_DIM / 4));
  gemm_enc<<<(M_DIM / 256) * (N_DIM / 256), 512, 0, stream>>>(x_h, w_h, b_enc, a1);
  topk_kernel<<<M_DIM, TK_THREADS, 0, stream>>>(a1, cand);
  refine_kernel<<<M_DIM, 256, 0, stream>>>(x, W, b_enc, cand, tk_idx, tk_val);
  decode_kernel<<<M_DIM, 256, 0, stream>>>(w_h, tk_idx, tk_val, b_dec, (float*)d_out);
}